// Round 1
// baseline (332.376 us; speedup 1.0000x reference)
//
#include <hip/hip_runtime.h>

#define Bn   2
#define CIN  64
#define COUT 64
#define Hd   192
#define Wd   192
#define HWd  (Hd*Wd)
#define Kk   9
#define NCh  20

// ---------------- K0: transpose weight [o][c][k] -> wt[k][c][o] ----------------
__global__ __launch_bounds__(256) void k0_transpose_w(const float* __restrict__ w,
                                                      float* __restrict__ wt) {
    int t = blockIdx.x * 256 + threadIdx.x;     // t = k*4096 + c*64 + o
    if (t >= Kk * CIN * COUT) return;
    int o = t & 63, c = (t >> 6) & 63, k = t >> 12;
    wt[t] = w[(o * CIN + c) * Kk + k];
}

// ---------------- K1: offset conv (3x3, 64->18, pad 1) ----------------
__global__ __launch_bounds__(256) void k1_offset_conv(const float* __restrict__ x,
        const float* __restrict__ off_w, const float* __restrict__ off_b,
        float* __restrict__ off) {
    __shared__ float wl[576 * 18];              // [c*9+tap][oc], 41.5 KB
    int tid = threadIdx.x;
    for (int idx = tid; idx < 18 * 576; idx += 256) {
        int oc = idx / 576, ct = idx % 576;
        wl[ct * 18 + oc] = off_w[idx];
    }
    __syncthreads();
    int t = blockIdx.x * 256 + tid;             // pixel id
    int j = t % Wd, i = (t / Wd) % Hd, b = t / HWd;
    float acc[18];
    #pragma unroll
    for (int oc = 0; oc < 18; ++oc) acc[oc] = off_b[oc];
    const float* xb = x + b * CIN * HWd;
    for (int c = 0; c < CIN; ++c) {
        const float* xc = xb + c * HWd;
        #pragma unroll
        for (int dy = 0; dy < 3; ++dy) {
            int yy = i + dy - 1;
            bool vy = (yy >= 0 && yy < Hd);
            #pragma unroll
            for (int dx = 0; dx < 3; ++dx) {
                int xx = j + dx - 1;
                float v = (vy && xx >= 0 && xx < Wd) ? xc[yy * Wd + xx] : 0.f;
                const float* wp = &wl[(c * 9 + dy * 3 + dx) * 18];
                #pragma unroll
                for (int oc = 0; oc < 18; ++oc) acc[oc] += v * wp[oc];
            }
        }
    }
    float* op = off + b * 18 * HWd + i * Wd + j;
    #pragma unroll
    for (int oc = 0; oc < 18; ++oc) op[oc * HWd] = acc[oc];
}

// ---------------- K2: mask via border-clamped bilinear + NC-dot ----------------
__global__ __launch_bounds__(256) void k2_mask(const float* __restrict__ inLO,
        const float* __restrict__ outLO, const float* __restrict__ off,
        float* __restrict__ mask) {
    int t = blockIdx.x * 256 + threadIdx.x;     // (b,k,i,j)
    int p = t % HWd;
    int k = (t / HWd) % Kk;
    int b = t / (Kk * HWd);
    int j = p % Wd, i = p / Wd;
    float offy = off[(b * 18 + 2 * k) * HWd + p];
    float offx = off[(b * 18 + 2 * k + 1) * HWd + p];
    float py = (float)(i + (k / 3)) + offy - 95.5f;
    float px = (float)(j + (k % 3)) + offx - 95.5f;
    py = fminf(fmaxf(py, 0.f), 191.f);
    px = fminf(fmaxf(px, 0.f), 191.f);
    float y0f = floorf(py), x0f = floorf(px);
    float ly = py - y0f, lx = px - x0f;
    int y0 = (int)y0f, x0 = (int)x0f;           // guaranteed in [0,191]
    int y1 = min(y0 + 1, Hd - 1), x1 = min(x0 + 1, Wd - 1);
    float w00 = (1.f - ly) * (1.f - lx);
    float w01 = (1.f - ly) * lx;
    float w10 = ly * (1.f - lx);
    float w11 = ly * lx;
    int i00 = y0 * Wd + x0, i01 = y0 * Wd + x1;
    int i10 = y1 * Wd + x0, i11 = y1 * Wd + x1;
    const float* LOb  = inLO  + b * NCh * HWd;
    const float* oLOb = outLO + b * NCh * HWd + p;
    float acc = 0.f;
    #pragma unroll 4
    for (int n = 0; n < NCh; ++n) {
        const float* L = LOb + n * HWd;
        float s = w00 * L[i00] + w01 * L[i01] + w10 * L[i10] + w11 * L[i11];
        acc += s * oLOb[n * HWd];
    }
    mask[(b * Kk + k) * HWd + p] = acc;
}

// ---------------- K3: main deformable conv as tiled GEMM ----------------
// block = 64 pixels (one row segment) x 64 outputs; per k: stage A (bilinear
// samples * mask) and B (weight slice) into LDS, 4x4 register tile / thread.
__global__ __launch_bounds__(256) void k3_main(const float* __restrict__ x,
        const float* __restrict__ off, const float* __restrict__ mask,
        const float* __restrict__ wt, const float* __restrict__ bias,
        float* __restrict__ out) {
    __shared__ float tapw[Kk][64][4];
    __shared__ int   tapi[Kk][64][4];
    __shared__ __align__(16) float As[64][64];  // [c][p]
    __shared__ __align__(16) float Bs[64][64];  // [c][o]
    int tid = threadIdx.x;
    int bid = blockIdx.x;
    int jt = bid % 3, i = (bid / 3) % Hd, b = bid / (3 * Hd);
    int j0 = jt * 64;

    // stage 1: per-(k,pixel) tap weights (mask folded in) + clamped indices
    for (int idx = tid; idx < Kk * 64; idx += 256) {
        int k = idx >> 6, p = idx & 63;
        int j = j0 + p;
        int pix = i * Wd + j;
        float offy = off[(b * 18 + 2 * k) * HWd + pix];
        float offx = off[(b * 18 + 2 * k + 1) * HWd + pix];
        float m = mask[(b * Kk + k) * HWd + pix];
        float py = (float)(i - 1 + (k / 3)) + offy;
        float px = (float)(j - 1 + (k % 3)) + offx;
        float y0f = floorf(py), x0f = floorf(px);
        float ly = py - y0f, lx = px - x0f;
        int y0 = (int)y0f, x0 = (int)x0f;
        int y1 = y0 + 1, x1 = x0 + 1;
        bool vy0 = (y0 >= 0 && y0 < Hd), vy1 = (y1 >= 0 && y1 < Hd);
        bool vx0 = (x0 >= 0 && x0 < Wd), vx1 = (x1 >= 0 && x1 < Wd);
        float w00 = (1.f - ly) * (1.f - lx) * m;
        float w01 = (1.f - ly) * lx * m;
        float w10 = ly * (1.f - lx) * m;
        float w11 = ly * lx * m;
        tapw[k][p][0] = (vy0 && vx0) ? w00 : 0.f;
        tapw[k][p][1] = (vy0 && vx1) ? w01 : 0.f;
        tapw[k][p][2] = (vy1 && vx0) ? w10 : 0.f;
        tapw[k][p][3] = (vy1 && vx1) ? w11 : 0.f;
        int y0c = min(max(y0, 0), Hd - 1), y1c = min(max(y1, 0), Hd - 1);
        int x0c = min(max(x0, 0), Wd - 1), x1c = min(max(x1, 0), Wd - 1);
        tapi[k][p][0] = y0c * Wd + x0c;
        tapi[k][p][1] = y0c * Wd + x1c;
        tapi[k][p][2] = y1c * Wd + x0c;
        tapi[k][p][3] = y1c * Wd + x1c;
    }

    float acc[4][4];
    #pragma unroll
    for (int a = 0; a < 4; ++a)
        #pragma unroll
        for (int q = 0; q < 4; ++q) acc[a][q] = 0.f;

    int p4 = (tid & 15) * 4;   // pixel sub-tile for GEMM
    int o4 = (tid >> 4) * 4;   // output sub-tile for GEMM
    int pA = tid & 63;         // pixel for A-staging
    int cg = tid >> 6;         // channel group 0..3 for A-staging
    const float* xb = x + b * CIN * HWd;
    __syncthreads();

    for (int k = 0; k < Kk; ++k) {
        // stage B: wt[k] is already [c][o], coalesced float4 copy
        const float4* wsrc = (const float4*)(wt + k * CIN * COUT);
        float4* bdst = (float4*)&Bs[0][0];
        for (int r = tid; r < 1024; r += 256) bdst[r] = wsrc[r];
        // stage A: each thread samples 16 channels for one pixel
        float w0 = tapw[k][pA][0], w1 = tapw[k][pA][1];
        float w2 = tapw[k][pA][2], w3 = tapw[k][pA][3];
        int i0 = tapi[k][pA][0], i1 = tapi[k][pA][1];
        int i2 = tapi[k][pA][2], i3 = tapi[k][pA][3];
        #pragma unroll 4
        for (int cc = 0; cc < 16; ++cc) {
            int c = cg * 16 + cc;
            const float* xc = xb + c * HWd;
            As[c][pA] = w0 * xc[i0] + w1 * xc[i1] + w2 * xc[i2] + w3 * xc[i3];
        }
        __syncthreads();
        // GEMM micro-step over 64 channels
        #pragma unroll 8
        for (int c = 0; c < 64; ++c) {
            float4 a  = *(const float4*)&As[c][p4];
            float4 bv = *(const float4*)&Bs[c][o4];
            acc[0][0] += a.x * bv.x; acc[0][1] += a.y * bv.x;
            acc[0][2] += a.z * bv.x; acc[0][3] += a.w * bv.x;
            acc[1][0] += a.x * bv.y; acc[1][1] += a.y * bv.y;
            acc[1][2] += a.z * bv.y; acc[1][3] += a.w * bv.y;
            acc[2][0] += a.x * bv.z; acc[2][1] += a.y * bv.z;
            acc[2][2] += a.z * bv.z; acc[2][3] += a.w * bv.z;
            acc[3][0] += a.x * bv.w; acc[3][1] += a.y * bv.w;
            acc[3][2] += a.z * bv.w; acc[3][3] += a.w * bv.w;
        }
        __syncthreads();
    }

    // epilogue: add bias, store float4 per output row
    #pragma unroll
    for (int oi = 0; oi < 4; ++oi) {
        int o = o4 + oi;
        float bval = bias[o];
        float4 r;
        r.x = acc[oi][0] + bval;
        r.y = acc[oi][1] + bval;
        r.z = acc[oi][2] + bval;
        r.w = acc[oi][3] + bval;
        *(float4*)(out + (b * COUT + o) * HWd + i * Wd + j0 + p4) = r;
    }
}

extern "C" void kernel_launch(void* const* d_in, const int* in_sizes, int n_in,
                              void* d_out, int out_size, void* d_ws, size_t ws_size,
                              hipStream_t stream) {
    const float* x      = (const float*)d_in[0];
    const float* inLO   = (const float*)d_in[1];
    const float* outLO  = (const float*)d_in[2];
    const float* weight = (const float*)d_in[3];
    const float* bias   = (const float*)d_in[4];
    const float* off_w  = (const float*)d_in[5];
    const float* off_b  = (const float*)d_in[6];
    float* out = (float*)d_out;

    float* off  = (float*)d_ws;                     // 2*18*36864 floats
    float* mask = off + Bn * 18 * HWd;              // 2*9*36864 floats
    float* wt   = mask + Bn * Kk * HWd;             // 9*64*64 floats

    k0_transpose_w<<<144, 256, 0, stream>>>(weight, wt);
    k1_offset_conv<<<288, 256, 0, stream>>>(x, off_w, off_b, off);
    k2_mask<<<2592, 256, 0, stream>>>(inLO, outLO, off, mask);
    k3_main<<<1152, 256, 0, stream>>>(x, off, mask, wt, bias, out);
}

// Round 5
// 270.811 us; speedup vs baseline: 1.2273x; 1.2273x over previous
//
#include <hip/hip_runtime.h>

#define Bn   2
#define CIN  64
#define COUT 64
#define Hd   192
#define Wd   192
#define HWd  (Hd*Wd)
#define Kk   9
#define NCh  20

// ---------------- kT: all layout transforms in one kernel ----------------
// blocks [0,1152)    : x [b][64][HW] -> xt [b][HW][64]      (64x64 LDS tiles)
// blocks [1152,1728) : in/outLO [b][20][HW] -> [b][HW][20]  (20x256 LDS tiles)
// blocks [1728,1872) : weight [o][c][k] -> wt [k][c][o]
// blocks [1872,1913) : off_w [oc][c][tap] -> owt [c][tap][oc]
__global__ __launch_bounds__(256) void kT(const float* __restrict__ x,
        const float* __restrict__ inLO, const float* __restrict__ outLO,
        const float* __restrict__ w, const float* __restrict__ off_w,
        float* __restrict__ xt, float* __restrict__ inLOt,
        float* __restrict__ outLOt, float* __restrict__ wt,
        float* __restrict__ owt) {
    __shared__ float lds[20 * 257];
    int bid = blockIdx.x, tid = threadIdx.x;
    if (bid < 1152) {                       // xt
        int b = bid / 576, p0 = (bid % 576) * 64;
        const float* src = x + b * CIN * HWd + p0;
        #pragma unroll
        for (int r = 0; r < 16; ++r) {
            int e = r * 256 + tid;          // e = c*64 + p
            int c = e >> 6, p = e & 63;
            lds[c * 65 + p] = src[c * HWd + p];
        }
        __syncthreads();
        float* dst = xt + (b * HWd + p0) * 64;
        #pragma unroll
        for (int r = 0; r < 16; ++r) {
            int e = r * 256 + tid;          // e = p*64 + c
            int p = e >> 6, c = e & 63;
            dst[e] = lds[c * 65 + p];
        }
    } else if (bid < 1728) {                // LO transposes
        int q = bid - 1152;
        int t = q / 288; q %= 288;
        int b = q / 144, p0 = (q % 144) * 256;
        const float* src = (t == 0 ? inLO : outLO) + b * NCh * HWd + p0;
        float* dst = (t == 0 ? inLOt : outLOt) + b * NCh * HWd + p0 * NCh;
        #pragma unroll
        for (int r = 0; r < 20; ++r) {
            int e = r * 256 + tid;          // e = n*256 + p
            int n = e >> 8, p = e & 255;
            lds[n * 257 + p] = src[n * HWd + p];
        }
        __syncthreads();
        #pragma unroll
        for (int r = 0; r < 20; ++r) {
            int e = r * 256 + tid;          // e = p*20 + n
            int p = e / 20, n = e % 20;
            dst[e] = lds[n * 257 + p];
        }
    } else if (bid < 1872) {                // wt
        int t = (bid - 1728) * 256 + tid;   // t = k*4096 + c*64 + o
        int o = t & 63, c = (t >> 6) & 63, k = t >> 12;
        wt[t] = w[(o * CIN + c) * Kk + k];
    } else {                                // owt
        int idx = (bid - 1872) * 256 + tid; // idx = (c*9+tap)*18 + oc
        if (idx < 18 * 576) {
            int oc = idx % 18, ct = idx / 18;
            int c = ct / 9, tap = ct % 9;
            owt[idx] = off_w[(oc * CIN + c) * Kk + tap];
        }
    }
}

// ---------------- k1: offset conv (3x3, 64->18, pad 1), SGPR weights ----------------
// grid 576: blockIdx&1 selects oc half (0..8 / 9..17); 256 pixels per block.
__global__ __launch_bounds__(256) void k1_offset_conv(const float* __restrict__ x,
        const float* __restrict__ owt, const float* __restrict__ off_b,
        float* __restrict__ off) {
    int tid = threadIdx.x;
    int half = blockIdx.x & 1;
    int oc0 = half * 9;
    int pix = (blockIdx.x >> 1) * 256 + tid;
    int b = pix / HWd, pp = pix % HWd;
    int jj = pp % Wd, ii = pp / Wd;
    float acc[9];
    #pragma unroll
    for (int q = 0; q < 9; ++q) acc[q] = off_b[oc0 + q];
    const float* xb = x + b * CIN * HWd;
    for (int c = 0; c < CIN; ++c) {
        const float* xc = xb + c * HWd;
        float v[9];
        #pragma unroll
        for (int dy = 0; dy < 3; ++dy) {
            int yy = ii + dy - 1;
            bool vy = (yy >= 0 && yy < Hd);
            #pragma unroll
            for (int dx = 0; dx < 3; ++dx) {
                int xx = jj + dx - 1;
                bool ok = vy && (xx >= 0) && (xx < Wd);
                int yc = min(max(yy, 0), Hd - 1);
                int xc2 = min(max(xx, 0), Wd - 1);
                float t = xc[yc * Wd + xc2];
                v[dy * 3 + dx] = ok ? t : 0.f;
            }
        }
        const float* wrow = owt + c * 9 * 18 + oc0;
        #pragma unroll
        for (int tap = 0; tap < 9; ++tap) {
            #pragma unroll
            for (int q = 0; q < 9; ++q)
                acc[q] += v[tap] * wrow[tap * 18 + q];
        }
    }
    float* op = off + b * 18 * HWd + pp;
    #pragma unroll
    for (int q = 0; q < 9; ++q) op[(oc0 + q) * HWd] = acc[q];
}

// ---------------- k2: mask via border-clamped bilinear + NC-dot (NHWC LO) ----------------
__global__ __launch_bounds__(256) void k2_mask(const float* __restrict__ inLOt,
        const float* __restrict__ outLOt, const float* __restrict__ off,
        float* __restrict__ mask) {
    int t = blockIdx.x * 256 + threadIdx.x;     // (b,k,i,j)
    int p = t % HWd;
    int k = (t / HWd) % Kk;
    int b = t / (Kk * HWd);
    int j = p % Wd, i = p / Wd;
    float offy = off[(b * 18 + 2 * k) * HWd + p];
    float offx = off[(b * 18 + 2 * k + 1) * HWd + p];
    float py = (float)(i + (k / 3)) + offy - 95.5f;
    float px = (float)(j + (k % 3)) + offx - 95.5f;
    py = fminf(fmaxf(py, 0.f), 191.f);
    px = fminf(fmaxf(px, 0.f), 191.f);
    float y0f = floorf(py), x0f = floorf(px);
    float ly = py - y0f, lx = px - x0f;
    int y0 = (int)y0f, x0 = (int)x0f;
    int y1 = min(y0 + 1, Hd - 1), x1 = min(x0 + 1, Wd - 1);
    float w00 = (1.f - ly) * (1.f - lx);
    float w01 = (1.f - ly) * lx;
    float w10 = ly * (1.f - lx);
    float w11 = ly * lx;
    const float4* L00 = (const float4*)(inLOt + (b * HWd + y0 * Wd + x0) * NCh);
    const float4* L01 = (const float4*)(inLOt + (b * HWd + y0 * Wd + x1) * NCh);
    const float4* L10 = (const float4*)(inLOt + (b * HWd + y1 * Wd + x0) * NCh);
    const float4* L11 = (const float4*)(inLOt + (b * HWd + y1 * Wd + x1) * NCh);
    const float4* O   = (const float4*)(outLOt + (b * HWd + p) * NCh);
    float acc = 0.f;
    #pragma unroll
    for (int n = 0; n < 5; ++n) {
        float4 a = L00[n], bb = L01[n], c = L10[n], d = L11[n], o = O[n];
        acc += (w00 * a.x + w01 * bb.x + w10 * c.x + w11 * d.x) * o.x;
        acc += (w00 * a.y + w01 * bb.y + w10 * c.y + w11 * d.y) * o.y;
        acc += (w00 * a.z + w01 * bb.z + w10 * c.z + w11 * d.z) * o.z;
        acc += (w00 * a.w + w01 * bb.w + w10 * c.w + w11 * d.w) * o.w;
    }
    mask[(b * Kk + k) * HWd + p] = acc;
}

// ---------------- K3: main deformable conv as tiled GEMM (NHWC gathers) ----------------
__global__ __launch_bounds__(256) void k3_main(const float* __restrict__ xt,
        const float* __restrict__ off, const float* __restrict__ mask,
        const float* __restrict__ wt, const float* __restrict__ bias,
        float* __restrict__ out) {
    __shared__ __align__(16) float As[64][64];  // [c][p]
    __shared__ __align__(16) float Bs[64][64];  // [c][o]
    int tid = threadIdx.x;
    int bid = blockIdx.x;
    int jt = bid % 3, i = (bid / 3) % Hd, b = bid / (3 * Hd);
    int j0 = jt * 64;

    float acc[4][4];
    #pragma unroll
    for (int a = 0; a < 4; ++a)
        #pragma unroll
        for (int q = 0; q < 4; ++q) acc[a][q] = 0.f;

    int p4 = (tid & 15) * 4;   // pixel sub-tile for GEMM
    int o4 = (tid >> 4) * 4;   // output sub-tile for GEMM
    int pA = tid & 63;         // pixel for A-staging
    int cg = tid >> 6;         // channel quarter (16 ch) for A-staging
    int pix = i * Wd + j0 + pA;
    const float4* x4 = (const float4*)(xt + (size_t)b * HWd * 64);

    for (int k = 0; k < Kk; ++k) {
        // stage B: wt[k] is [c][o], coalesced float4 copy
        const float4* wsrc = (const float4*)(wt + k * CIN * COUT);
        float4* bdst = (float4*)&Bs[0][0];
        #pragma unroll
        for (int r = 0; r < 4; ++r) bdst[r * 256 + tid] = wsrc[r * 256 + tid];

        // per-thread tap computation (registers, no LDS)
        float offy = off[(b * 18 + 2 * k) * HWd + pix];
        float offx = off[(b * 18 + 2 * k + 1) * HWd + pix];
        float m = mask[(b * Kk + k) * HWd + pix];
        float py = (float)(i - 1 + (k / 3)) + offy;
        float px = (float)(j0 + pA - 1 + (k % 3)) + offx;
        float y0f = floorf(py), x0f = floorf(px);
        float ly = py - y0f, lx = px - x0f;
        int y0 = (int)y0f, x0 = (int)x0f;
        int y1 = y0 + 1, x1 = x0 + 1;
        bool vy0 = (y0 >= 0 && y0 < Hd), vy1 = (y1 >= 0 && y1 < Hd);
        bool vx0 = (x0 >= 0 && x0 < Wd), vx1 = (x1 >= 0 && x1 < Wd);
        float w00 = (vy0 && vx0) ? (1.f - ly) * (1.f - lx) * m : 0.f;
        float w01 = (vy0 && vx1) ? (1.f - ly) * lx * m : 0.f;
        float w10 = (vy1 && vx0) ? ly * (1.f - lx) * m : 0.f;
        float w11 = (vy1 && vx1) ? ly * lx * m : 0.f;
        int y0c = min(max(y0, 0), Hd - 1), y1c = min(max(y1, 0), Hd - 1);
        int x0c = min(max(x0, 0), Wd - 1), x1c = min(max(x1, 0), Wd - 1);
        int i00 = (y0c * Wd + x0c) * 16 + cg * 4;   // in float4 units
        int i01 = (y0c * Wd + x1c) * 16 + cg * 4;
        int i10 = (y1c * Wd + x0c) * 16 + cg * 4;
        int i11 = (y1c * Wd + x1c) * 16 + cg * 4;

        // gather 4 taps x 16 contiguous channels, combine, write As
        #pragma unroll
        for (int wv = 0; wv < 4; ++wv) {
            float4 g00 = x4[i00 + wv];
            float4 g01 = x4[i01 + wv];
            float4 g10 = x4[i10 + wv];
            float4 g11 = x4[i11 + wv];
            float4 s;
            s.x = w00 * g00.x + w01 * g01.x + w10 * g10.x + w11 * g11.x;
            s.y = w00 * g00.y + w01 * g01.y + w10 * g10.y + w11 * g11.y;
            s.z = w00 * g00.z + w01 * g01.z + w10 * g10.z + w11 * g11.z;
            s.w = w00 * g00.w + w01 * g01.w + w10 * g10.w + w11 * g11.w;
            int c0 = cg * 16 + wv * 4;
            As[c0 + 0][pA] = s.x;
            As[c0 + 1][pA] = s.y;
            As[c0 + 2][pA] = s.z;
            As[c0 + 3][pA] = s.w;
        }
        __syncthreads();

        // GEMM micro-step over 64 channels
        #pragma unroll 16
        for (int c = 0; c < 64; ++c) {
            float4 a  = *(const float4*)&As[c][p4];
            float4 bv = *(const float4*)&Bs[c][o4];
            acc[0][0] += a.x * bv.x; acc[0][1] += a.y * bv.x;
            acc[0][2] += a.z * bv.x; acc[0][3] += a.w * bv.x;
            acc[1][0] += a.x * bv.y; acc[1][1] += a.y * bv.y;
            acc[1][2] += a.z * bv.y; acc[1][3] += a.w * bv.y;
            acc[2][0] += a.x * bv.z; acc[2][1] += a.y * bv.z;
            acc[2][2] += a.z * bv.z; acc[2][3] += a.w * bv.z;
            acc[3][0] += a.x * bv.w; acc[3][1] += a.y * bv.w;
            acc[3][2] += a.z * bv.w; acc[3][3] += a.w * bv.w;
        }
        __syncthreads();
    }

    // epilogue: add bias, store float4 per output row
    #pragma unroll
    for (int oi = 0; oi < 4; ++oi) {
        int o = o4 + oi;
        float bval = bias[o];
        float4 r;
        r.x = acc[oi][0] + bval;
        r.y = acc[oi][1] + bval;
        r.z = acc[oi][2] + bval;
        r.w = acc[oi][3] + bval;
        *(float4*)(out + (b * COUT + o) * HWd + i * Wd + j0 + p4) = r;
    }
}

extern "C" void kernel_launch(void* const* d_in, const int* in_sizes, int n_in,
                              void* d_out, int out_size, void* d_ws, size_t ws_size,
                              hipStream_t stream) {
    const float* x      = (const float*)d_in[0];
    const float* inLO   = (const float*)d_in[1];
    const float* outLO  = (const float*)d_in[2];
    const float* weight = (const float*)d_in[3];
    const float* bias   = (const float*)d_in[4];
    const float* off_w  = (const float*)d_in[5];
    const float* off_b  = (const float*)d_in[6];
    float* out = (float*)d_out;

    float* off    = (float*)d_ws;                   // 2*18*36864
    float* mask   = off    + Bn * 18 * HWd;         // 2*9*36864
    float* wt     = mask   + Bn * Kk * HWd;         // 9*64*64
    float* owt    = wt     + Kk * CIN * COUT;       // 576*18
    float* xt     = owt    + 576 * 18;              // 2*36864*64
    float* inLOt  = xt     + (size_t)Bn * HWd * CIN;
    float* outLOt = inLOt  + (size_t)Bn * HWd * NCh;

    kT<<<1913, 256, 0, stream>>>(x, inLO, outLO, weight, off_w,
                                 xt, inLOt, outLOt, wt, owt);
    k1_offset_conv<<<576, 256, 0, stream>>>(x, owt, off_b, off);
    k2_mask<<<2592, 256, 0, stream>>>(inLOt, outLOt, off, mask);
    k3_main<<<1152, 256, 0, stream>>>(xt, off, mask, wt, bias, out);
}

// Round 6
// 255.917 us; speedup vs baseline: 1.2988x; 1.0582x over previous
//
#include <hip/hip_runtime.h>

#define Bn   2
#define CIN  64
#define COUT 64
#define Hd   192
#define Wd   192
#define HWd  (Hd*Wd)
#define Kk   9
#define NCh  20

typedef __attribute__((ext_vector_type(8))) short short8;
typedef __attribute__((ext_vector_type(4))) float f32x4;

static __device__ __forceinline__ ushort f2bf(float f) {
    unsigned u = __float_as_uint(f);
    u += 0x7fffu + ((u >> 16) & 1u);        // round-to-nearest-even
    return (ushort)(u >> 16);
}

// ---------------- kT: all layout transforms in one kernel ----------------
// blocks [0,1152)    : x [b][64][HW] -> xt [b][HW][64]      (64x64 LDS tiles)
// blocks [1152,1728) : in/outLO [b][20][HW] -> [b][HW][20]  (20x256 LDS tiles)
// blocks [1728,1872) : weight [o][c][k] -> wtb bf16 fragment-order
//                      [tap][ntile4][ktile2][lane64][e8]
// blocks [1872,1913) : off_w [oc][c][tap] -> owt [c][tap][oc]
__global__ __launch_bounds__(256) void kT(const float* __restrict__ x,
        const float* __restrict__ inLO, const float* __restrict__ outLO,
        const float* __restrict__ w, const float* __restrict__ off_w,
        float* __restrict__ xt, float* __restrict__ inLOt,
        float* __restrict__ outLOt, ushort* __restrict__ wtb,
        float* __restrict__ owt) {
    __shared__ float lds[20 * 257];
    int bid = blockIdx.x, tid = threadIdx.x;
    if (bid < 1152) {                       // xt
        int b = bid / 576, p0 = (bid % 576) * 64;
        const float* src = x + b * CIN * HWd + p0;
        #pragma unroll
        for (int r = 0; r < 16; ++r) {
            int e = r * 256 + tid;          // e = c*64 + p
            int c = e >> 6, p = e & 63;
            lds[c * 65 + p] = src[c * HWd + p];
        }
        __syncthreads();
        float* dst = xt + (b * HWd + p0) * 64;
        #pragma unroll
        for (int r = 0; r < 16; ++r) {
            int e = r * 256 + tid;          // e = p*64 + c
            int p = e >> 6, c = e & 63;
            dst[e] = lds[c * 65 + p];
        }
    } else if (bid < 1728) {                // LO transposes
        int q = bid - 1152;
        int t = q / 288; q %= 288;
        int b = q / 144, p0 = (q % 144) * 256;
        const float* src = (t == 0 ? inLO : outLO) + b * NCh * HWd + p0;
        float* dst = (t == 0 ? inLOt : outLOt) + b * NCh * HWd + p0 * NCh;
        #pragma unroll
        for (int r = 0; r < 20; ++r) {
            int e = r * 256 + tid;          // e = n*256 + p
            int n = e >> 8, p = e & 255;
            lds[n * 257 + p] = src[n * HWd + p];
        }
        __syncthreads();
        #pragma unroll
        for (int r = 0; r < 20; ++r) {
            int e = r * 256 + tid;          // e = p*20 + n
            int p = e / 20, n = e % 20;
            dst[e] = lds[n * 257 + p];
        }
    } else if (bid < 1872) {                // wtb (bf16, MFMA B-fragment order)
        int f = (bid - 1728) * 256 + tid;   // 36864 total
        int e = f & 7, lane = (f >> 3) & 63;
        int kt = (f >> 9) & 1, nt = (f >> 10) & 3, tap = f >> 12;
        int o = nt * 16 + (lane & 15);
        int c = kt * 32 + (lane >> 4) * 8 + e;
        wtb[f] = f2bf(w[(o * CIN + c) * Kk + tap]);
    } else {                                // owt
        int idx = (bid - 1872) * 256 + tid; // idx = (c*9+tap)*18 + oc
        if (idx < 18 * 576) {
            int oc = idx % 18, ct = idx / 18;
            int c = ct / 9, tap = ct % 9;
            owt[idx] = off_w[(oc * CIN + c) * Kk + tap];
        }
    }
}

// ---------------- k1: offset conv (3x3, 64->18, pad 1) ----------------
__global__ __launch_bounds__(256) void k1_offset_conv(const float* __restrict__ x,
        const float* __restrict__ owt, const float* __restrict__ off_b,
        float* __restrict__ off) {
    int tid = threadIdx.x;
    int half = blockIdx.x & 1;
    int oc0 = half * 9;
    int pix = (blockIdx.x >> 1) * 256 + tid;
    int b = pix / HWd, pp = pix % HWd;
    int jj = pp % Wd, ii = pp / Wd;
    float acc[9];
    #pragma unroll
    for (int q = 0; q < 9; ++q) acc[q] = off_b[oc0 + q];
    const float* xb = x + b * CIN * HWd;
    for (int c = 0; c < CIN; ++c) {
        const float* xc = xb + c * HWd;
        float v[9];
        #pragma unroll
        for (int dy = 0; dy < 3; ++dy) {
            int yy = ii + dy - 1;
            bool vy = (yy >= 0 && yy < Hd);
            #pragma unroll
            for (int dx = 0; dx < 3; ++dx) {
                int xx = jj + dx - 1;
                bool ok = vy && (xx >= 0) && (xx < Wd);
                int yc = min(max(yy, 0), Hd - 1);
                int xc2 = min(max(xx, 0), Wd - 1);
                float t = xc[yc * Wd + xc2];
                v[dy * 3 + dx] = ok ? t : 0.f;
            }
        }
        const float* wrow = owt + c * 9 * 18 + oc0;
        #pragma unroll
        for (int tap = 0; tap < 9; ++tap) {
            #pragma unroll
            for (int q = 0; q < 9; ++q)
                acc[q] += v[tap] * wrow[tap * 18 + q];
        }
    }
    float* op = off + b * 18 * HWd + pp;
    #pragma unroll
    for (int q = 0; q < 9; ++q) op[(oc0 + q) * HWd] = acc[q];
}

// ---------------- k2: mask via border-clamped bilinear + NC-dot (NHWC LO) ----------------
__global__ __launch_bounds__(256) void k2_mask(const float* __restrict__ inLOt,
        const float* __restrict__ outLOt, const float* __restrict__ off,
        float* __restrict__ mask) {
    int t = blockIdx.x * 256 + threadIdx.x;     // (b,k,i,j)
    int p = t % HWd;
    int k = (t / HWd) % Kk;
    int b = t / (Kk * HWd);
    int j = p % Wd, i = p / Wd;
    float offy = off[(b * 18 + 2 * k) * HWd + p];
    float offx = off[(b * 18 + 2 * k + 1) * HWd + p];
    float py = (float)(i + (k / 3)) + offy - 95.5f;
    float px = (float)(j + (k % 3)) + offx - 95.5f;
    py = fminf(fmaxf(py, 0.f), 191.f);
    px = fminf(fmaxf(px, 0.f), 191.f);
    float y0f = floorf(py), x0f = floorf(px);
    float ly = py - y0f, lx = px - x0f;
    int y0 = (int)y0f, x0 = (int)x0f;
    int y1 = min(y0 + 1, Hd - 1), x1 = min(x0 + 1, Wd - 1);
    float w00 = (1.f - ly) * (1.f - lx);
    float w01 = (1.f - ly) * lx;
    float w10 = ly * (1.f - lx);
    float w11 = ly * lx;
    const float4* L00 = (const float4*)(inLOt + (b * HWd + y0 * Wd + x0) * NCh);
    const float4* L01 = (const float4*)(inLOt + (b * HWd + y0 * Wd + x1) * NCh);
    const float4* L10 = (const float4*)(inLOt + (b * HWd + y1 * Wd + x0) * NCh);
    const float4* L11 = (const float4*)(inLOt + (b * HWd + y1 * Wd + x1) * NCh);
    const float4* O   = (const float4*)(outLOt + (b * HWd + p) * NCh);
    float acc = 0.f;
    #pragma unroll
    for (int n = 0; n < 5; ++n) {
        float4 a = L00[n], bb = L01[n], c = L10[n], d = L11[n], o = O[n];
        acc += (w00 * a.x + w01 * bb.x + w10 * c.x + w11 * d.x) * o.x;
        acc += (w00 * a.y + w01 * bb.y + w10 * c.y + w11 * d.y) * o.y;
        acc += (w00 * a.z + w01 * bb.z + w10 * c.z + w11 * d.z) * o.z;
        acc += (w00 * a.w + w01 * bb.w + w10 * c.w + w11 * d.w) * o.w;
    }
    mask[(b * Kk + k) * HWd + p] = acc;
}

// ---------------- K3: deformable conv, bf16 MFMA GEMM ----------------
// block = 64 px x 64 out, 4 waves (2x2, each 32x32).
// A staged in LDS in MFMA A-fragment order [mt4][kt2][lane64][e8] bf16;
// B read from global fragment-ordered bf16 straight into VGPRs (L2-hit).
__global__ __launch_bounds__(256) void k3_main(const float* __restrict__ xt,
        const float* __restrict__ off, const float* __restrict__ mask,
        const ushort* __restrict__ wtb, const float* __restrict__ bias,
        float* __restrict__ out) {
    __shared__ __align__(16) ushort A_lds[4 * 2 * 64 * 8];   // 8 KB
    int tid = threadIdx.x;
    int bid = blockIdx.x;
    int jt = bid % 3, i = (bid / 3) % Hd, b = bid / (3 * Hd);
    int j0 = jt * 64;

    int lane = tid & 63;
    int wv_id = tid >> 6;          // wave 0..3
    int wm = wv_id >> 1;           // 0/1 -> m32 = wm*32
    int wn = wv_id & 1;            // 0/1 -> n32 = wn*32

    int pA = tid & 63;             // pixel this thread stages
    int cg = tid >> 6;             // channel quarter (16 ch)
    int pix = i * Wd + j0 + pA;
    const float4* x4 = (const float4*)(xt + (size_t)b * HWd * 64);

    f32x4 acc[2][2];
    #pragma unroll
    for (int mi = 0; mi < 2; ++mi)
        #pragma unroll
        for (int ni = 0; ni < 2; ++ni)
            acc[mi][ni] = (f32x4){0.f, 0.f, 0.f, 0.f};

    int mt_w = pA >> 4, row_w = pA & 15, kt_w = cg >> 1;   // A-write coords

    for (int k = 0; k < Kk; ++k) {
        // B fragments: global, fragment-ordered, lane-linear dwordx4 (L2-hit)
        short8 bf[2][2];
        #pragma unroll
        for (int kt = 0; kt < 2; ++kt)
            #pragma unroll
            for (int ni = 0; ni < 2; ++ni) {
                int nt = wn * 2 + ni;
                bf[kt][ni] = *(const short8*)(wtb +
                    ((((k * 4 + nt) * 2 + kt) * 64 + lane) << 3));
            }

        // per-thread tap computation (registers)
        float offy = off[(b * 18 + 2 * k) * HWd + pix];
        float offx = off[(b * 18 + 2 * k + 1) * HWd + pix];
        float m = mask[(b * Kk + k) * HWd + pix];
        float py = (float)(i - 1 + (k / 3)) + offy;
        float px = (float)(j0 + pA - 1 + (k % 3)) + offx;
        float y0f = floorf(py), x0f = floorf(px);
        float ly = py - y0f, lx = px - x0f;
        int y0 = (int)y0f, x0 = (int)x0f;
        int y1 = y0 + 1, x1 = x0 + 1;
        bool vy0 = (y0 >= 0 && y0 < Hd), vy1 = (y1 >= 0 && y1 < Hd);
        bool vx0 = (x0 >= 0 && x0 < Wd), vx1 = (x1 >= 0 && x1 < Wd);
        float w00 = (vy0 && vx0) ? (1.f - ly) * (1.f - lx) * m : 0.f;
        float w01 = (vy0 && vx1) ? (1.f - ly) * lx * m : 0.f;
        float w10 = (vy1 && vx0) ? ly * (1.f - lx) * m : 0.f;
        float w11 = (vy1 && vx1) ? ly * lx * m : 0.f;
        int y0c = min(max(y0, 0), Hd - 1), y1c = min(max(y1, 0), Hd - 1);
        int x0c = min(max(x0, 0), Wd - 1), x1c = min(max(x1, 0), Wd - 1);
        int i00 = (y0c * Wd + x0c) * 16 + cg * 4;   // float4 units
        int i01 = (y0c * Wd + x1c) * 16 + cg * 4;
        int i10 = (y1c * Wd + x0c) * 16 + cg * 4;
        int i11 = (y1c * Wd + x1c) * 16 + cg * 4;

        // sample 16 channels, convert to bf16
        ushort sv[16];
        #pragma unroll
        for (int g = 0; g < 4; ++g) {
            float4 g00 = x4[i00 + g];
            float4 g01 = x4[i01 + g];
            float4 g10 = x4[i10 + g];
            float4 g11 = x4[i11 + g];
            sv[g * 4 + 0] = f2bf(w00 * g00.x + w01 * g01.x + w10 * g10.x + w11 * g11.x);
            sv[g * 4 + 1] = f2bf(w00 * g00.y + w01 * g01.y + w10 * g10.y + w11 * g11.y);
            sv[g * 4 + 2] = f2bf(w00 * g00.z + w01 * g01.z + w10 * g10.z + w11 * g11.z);
            sv[g * 4 + 3] = f2bf(w00 * g00.w + w01 * g01.w + w10 * g10.w + w11 * g11.w);
        }
        // write A fragments (2 x b128, lane-linear within wave)
        #pragma unroll
        for (int h = 0; h < 2; ++h) {
            short8 pk;
            #pragma unroll
            for (int e = 0; e < 8; ++e) pk[e] = (short)sv[h * 8 + e];
            int lw = ((cg & 1) * 2 + h) * 16 + row_w;
            *(short8*)&A_lds[(((mt_w * 2 + kt_w) * 64 + lw) << 3)] = pk;
        }
        __syncthreads();

        // MFMA: 8 per wave per tap
        #pragma unroll
        for (int kt = 0; kt < 2; ++kt) {
            #pragma unroll
            for (int mi = 0; mi < 2; ++mi) {
                int mt2 = wm * 2 + mi;
                short8 af = *(const short8*)&A_lds[(((mt2 * 2 + kt) * 64 + lane) << 3)];
                acc[mi][0] = __builtin_amdgcn_mfma_f32_16x16x32_bf16(
                                 af, bf[kt][0], acc[mi][0], 0, 0, 0);
                acc[mi][1] = __builtin_amdgcn_mfma_f32_16x16x32_bf16(
                                 af, bf[kt][1], acc[mi][1], 0, 0, 0);
            }
        }
        __syncthreads();
    }

    // epilogue: D frag layout col=lane&15 (o), row=(lane>>4)*4+reg (pixel)
    int colo = lane & 15;
    int rb = (lane >> 4) * 4;
    #pragma unroll
    for (int ni = 0; ni < 2; ++ni) {
        int o = wn * 32 + ni * 16 + colo;
        float bv = bias[o];
        #pragma unroll
        for (int mi = 0; mi < 2; ++mi) {
            int p0 = wm * 32 + mi * 16 + rb;
            float4 r;
            r.x = acc[mi][ni][0] + bv;
            r.y = acc[mi][ni][1] + bv;
            r.z = acc[mi][ni][2] + bv;
            r.w = acc[mi][ni][3] + bv;
            *(float4*)(out + ((size_t)(b * COUT + o) * HWd) + i * Wd + j0 + p0) = r;
        }
    }
}

extern "C" void kernel_launch(void* const* d_in, const int* in_sizes, int n_in,
                              void* d_out, int out_size, void* d_ws, size_t ws_size,
                              hipStream_t stream) {
    const float* x      = (const float*)d_in[0];
    const float* inLO   = (const float*)d_in[1];
    const float* outLO  = (const float*)d_in[2];
    const float* weight = (const float*)d_in[3];
    const float* bias   = (const float*)d_in[4];
    const float* off_w  = (const float*)d_in[5];
    const float* off_b  = (const float*)d_in[6];
    float* out = (float*)d_out;

    float*  off    = (float*)d_ws;                  // 2*18*36864
    float*  mask   = off    + Bn * 18 * HWd;        // 2*9*36864
    ushort* wtb    = (ushort*)(mask + Bn * Kk * HWd);  // 36864 bf16 (in old wt slot)
    float*  owt    = (float*)(mask + Bn * Kk * HWd) + Kk * CIN * COUT;
    float*  xt     = owt    + 576 * 18;             // 2*36864*64
    float*  inLOt  = xt     + (size_t)Bn * HWd * CIN;
    float*  outLOt = inLOt  + (size_t)Bn * HWd * NCh;

    kT<<<1913, 256, 0, stream>>>(x, inLO, outLO, weight, off_w,
                                 xt, inLOt, outLOt, wtb, owt);
    k1_offset_conv<<<576, 256, 0, stream>>>(x, owt, off_b, off);
    k2_mask<<<2592, 256, 0, stream>>>(inLOt, outLOt, off, mask);
    k3_main<<<1152, 256, 0, stream>>>(xt, off, mask, wtb, bias, out);
}